// Round 4
// baseline (670.460 us; speedup 1.0000x reference)
//
#include <hip/hip_runtime.h>
#include <hip/hip_cooperative_groups.h>
#include <math.h>

namespace cg = cooperative_groups;

// Problem constants (B=1, C=256, W=64, N=4096, D=256)
#define N_TOK 4096

// workspace layout (float offsets)
#define OFF_GU    0        // 1024  : g[c]*u[c] per modality
#define OFF_GUP   1024     // 32    : GU partials (4 modalities x 8 blocks)
#define OFF_BUP   1056     // 32    : BU partials
#define OFF_SIM   2048     // 16384
#define OFF_MU    18432    // 16384
#define OFF_RINV  34816    // 16384
#define OFF_BLK   51200    // 48    : softmax block partials {mx, sumexp, sum e*rinv*mu}
#define OFF_W     51264    // 1024  : weighted channel sums per modality
#define OFF_OUTV  52288    // 256   : attention output vector (atomic)
#define OFF_R     52544    // 256   : layernormed outv
#define OFF_GG    52800    // 512   : geglu pre-activation (atomic, init b_geglu)
#define OFF_FF    53312    // 256   : ff2 output (atomic, init b_ff2)
#define OFF_Y     53568    // 256   : final channel vector (atomic, init b_out)
// extra slots for the fallback pipeline
#define OFF_Q     53824    // 256   : q accumulator (fallback only)
#define OFF_SOFT  54080    // 10    : fallback softmax combine

struct Params {
  const float *x, *h, *s, *m, *t, *wt, *bt;
  const float *wk0, *wv0, *g0, *be0;
  const float *wk1, *wv1, *g1, *be1;
  const float *wk2, *wv2, *g2, *be2;
  const float *wk3, *wv3, *g3, *be3;
  const float *w_geglu, *b_geglu, *w_ff2, *b_ff2;
  const float *g_res, *be_res, *w_out, *b_out;
  float* ws;
  float4* out4;
};

// ===========================================================================
// Cooperative fused kernel: 512 blocks x 256 threads, needs 2 blocks/CU.
// __launch_bounds__(256,2) -> VGPR cap 256 (always satisfiable) -> 2 blocks/CU.
__global__ __launch_bounds__(256, 2) void fused(Params p) {
  cg::grid_group grid = cg::this_grid();
  const int gid = blockIdx.x;   // 0..511
  const int tid = threadIdx.x;  // 0..255
  float* ws = p.ws;

  __shared__ float sh[3328];    // 13 KB: max over phases

  const float* Aarr[4] = {p.x, p.h, p.s, p.m};
  const float* garr[4] = {p.g0, p.g1, p.g2, p.g3};
  const float* bearr[4] = {p.be0, p.be1, p.be2, p.be3};

  // ---- P0: blocks 0..31: q (redundant) -> u rows -> gu, GU/BU partials.
  //          block 32: init atomic accumulators with biases.
  if (gid < 32) {
    const int m = gid >> 3;
    const int c0 = (gid & 7) * 32;
    const float* wkarr[4] = {p.wk0, p.wk1, p.wk2, p.wk3};
    const float* wk = wkarr[m];
    const float* g = garr[m];
    const float* be = bearr[m];

    float acc = p.bt[tid];
    #pragma unroll 8
    for (int c = 0; c < 256; ++c) acc += p.t[c] * p.wt[c * 256 + tid];
    sh[tid] = acc;               // q
    __syncthreads();

    const int w = tid >> 6, lane = tid & 63;
    const float4 qv = ((const float4*)sh)[lane];
    float lGU = 0.f, lBU = 0.f;
    #pragma unroll
    for (int r = 0; r < 8; ++r) {
      int c = c0 + w * 8 + r;
      float4 w4 = ((const float4*)(wk + c * 256))[lane];
      float sdot = w4.x * qv.x + w4.y * qv.y + w4.z * qv.z + w4.w * qv.w;
      for (int o = 32; o > 0; o >>= 1) sdot += __shfl_down(sdot, o, 64);
      if (lane == 0) {
        float u = sdot;
        float gu = g[c] * u;
        ws[OFF_GU + m * 256 + c] = gu;
        lGU += gu;
        lBU += be[c] * u;
      }
    }
    __syncthreads();             // reuse sh[256..]
    if (lane == 0) { sh[256 + w] = lGU; sh[260 + w] = lBU; }
    __syncthreads();
    if (tid == 0) {
      ws[OFF_GUP + m * 8 + (gid & 7)] = sh[256] + sh[257] + sh[258] + sh[259];
      ws[OFF_BUP + m * 8 + (gid & 7)] = sh[260] + sh[261] + sh[262] + sh[263];
    }
  } else if (gid == 32) {
    ws[OFF_OUTV + tid] = 0.0f;
    ws[OFF_GG + tid] = p.b_geglu[tid];
    ws[OFF_GG + 256 + tid] = p.b_geglu[256 + tid];
    ws[OFF_FF + tid] = p.b_ff2[tid];
    ws[OFF_Y + tid] = p.b_out[tid];
  }
  grid.sync();

  // ---- P1: 512 blocks: per-token stats + sim. 32 tokens per block.
  {
    const int m = gid >> 7;            // 128 blocks per modality
    const int jbase = (gid & 127) * 32;
    const int l = tid & 7;             // token float4 group (tokens l*4..l*4+3)
    const int qg = tid >> 3;           // 32 channel groups of 8
    const float* A = Aarr[m];

    float* gu_sh = sh;                 // 256
    float* p1 = sh + 256;              // 1024
    float* p2 = sh + 1280;             // 1024
    float* p3 = sh + 2304;             // 1024
    gu_sh[tid] = ws[OFF_GU + m * 256 + tid];
    __syncthreads();

    float s1[4] = {0, 0, 0, 0}, s2[4] = {0, 0, 0, 0}, s3[4] = {0, 0, 0, 0};
    #pragma unroll
    for (int i = 0; i < 8; ++i) {
      int c = qg * 8 + i;
      float4 v4 = ((const float4*)(A + c * N_TOK + jbase))[l];
      float gv = gu_sh[c];
      s1[0] += v4.x; s2[0] += v4.x * v4.x; s3[0] += v4.x * gv;
      s1[1] += v4.y; s2[1] += v4.y * v4.y; s3[1] += v4.y * gv;
      s1[2] += v4.z; s2[2] += v4.z * v4.z; s3[2] += v4.z * gv;
      s1[3] += v4.w; s2[3] += v4.w * v4.w; s3[3] += v4.w * gv;
    }
    #pragma unroll
    for (int k = 0; k < 4; ++k) {
      int tok = l * 4 + k;
      p1[qg * 32 + tok] = s1[k];
      p2[qg * 32 + tok] = s2[k];
      p3[qg * 32 + tok] = s3[k];
    }
    __syncthreads();
    if (tid < 32) {
      float S1 = 0.f, S2 = 0.f, S3 = 0.f;
      #pragma unroll 8
      for (int q = 0; q < 32; ++q) {
        S1 += p1[q * 32 + tid];
        S2 += p2[q * 32 + tid];
        S3 += p3[q * 32 + tid];
      }
      float GU = 0.f, BU = 0.f;
      #pragma unroll
      for (int i = 0; i < 8; ++i) {
        GU += ws[OFF_GUP + m * 8 + i];
        BU += ws[OFF_BUP + m * 8 + i];
      }
      float mu = S1 * (1.0f / 256.0f);
      float var = S2 * (1.0f / 256.0f) - mu * mu;
      float rinv = rsqrtf(var + 1e-5f);
      float sim = 0.0625f * (rinv * (S3 - mu * GU) + BU);
      int gj = m * N_TOK + jbase + tid;
      ws[OFF_SIM + gj] = sim;
      ws[OFF_MU + gj] = mu;
      ws[OFF_RINV + gj] = rinv;
    }
  }
  grid.sync();

  // ---- P2: blocks 0..15: softmax partials over 1024 sims each.
  if (gid < 16) {
    const int base = gid * 1024;
    float v[4];
    float mx = -1e30f;
    #pragma unroll
    for (int i = 0; i < 4; ++i) {
      v[i] = ws[OFF_SIM + base + i * 256 + tid];
      mx = fmaxf(mx, v[i]);
    }
    for (int o = 32; o > 0; o >>= 1) mx = fmaxf(mx, __shfl_down(mx, o, 64));
    if ((tid & 63) == 0) sh[tid >> 6] = mx;
    __syncthreads();
    const float mxb = fmaxf(fmaxf(sh[0], sh[1]), fmaxf(sh[2], sh[3]));
    __syncthreads();
    float se = 0.f, srm = 0.f;
    #pragma unroll
    for (int i = 0; i < 4; ++i) {
      int idx = base + i * 256 + tid;
      float e = expf(v[i] - mxb);
      se += e;
      srm += e * ws[OFF_RINV + idx] * ws[OFF_MU + idx];
    }
    for (int o = 32; o > 0; o >>= 1) se += __shfl_down(se, o, 64);
    if ((tid & 63) == 0) sh[tid >> 6] = se;
    __syncthreads();
    float seT = sh[0] + sh[1] + sh[2] + sh[3];
    __syncthreads();
    for (int o = 32; o > 0; o >>= 1) srm += __shfl_down(srm, o, 64);
    if ((tid & 63) == 0) sh[tid >> 6] = srm;
    __syncthreads();
    if (tid == 0) {
      ws[OFF_BLK + gid * 3 + 0] = mxb;
      ws[OFF_BLK + gid * 3 + 1] = seT;
      ws[OFF_BLK + gid * 3 + 2] = sh[0] + sh[1] + sh[2] + sh[3];
    }
  }
  grid.sync();

  // ---- P3: 512 blocks: wfin per (m,c) with inline softmax combine; 2 rows/block.
  {
    const int m = gid >> 7;
    const int cbase = (gid & 127) * 2;

    float M = -1e30f;
    #pragma unroll
    for (int b = 0; b < 16; ++b) M = fmaxf(M, ws[OFF_BLK + b * 3]);
    float S = 0.f, Asm = 0.f, Pm = 0.f;
    #pragma unroll
    for (int b = 0; b < 16; ++b) {
      float f = expf(ws[OFF_BLK + b * 3] - M);
      float sef = ws[OFF_BLK + b * 3 + 1] * f;
      S += sef;
      if ((b >> 2) == m) {
        Asm += sef;
        Pm += ws[OFF_BLK + b * 3 + 2] * f;
      }
    }
    const float inv = 1.0f / S;

    for (int r = 0; r < 2; ++r) {
      const int c = cbase + r;
      const float* row = Aarr[m] + c * N_TOK;
      float sacc = 0.f;
      #pragma unroll 4
      for (int i = 0; i < 16; ++i) {
        int j = i * 256 + tid;
        int gj = m * N_TOK + j;
        float a = expf(ws[OFF_SIM + gj] - M) * ws[OFF_RINV + gj];
        sacc += a * row[j];
      }
      for (int o = 32; o > 0; o >>= 1) sacc += __shfl_down(sacc, o, 64);
      if ((tid & 63) == 0) sh[tid >> 6] = sacc;
      __syncthreads();
      if (tid == 0) {
        float dot = (sh[0] + sh[1] + sh[2] + sh[3]) * inv;
        ws[OFF_W + m * 256 + c] =
            garr[m][c] * (dot - Pm * inv) + bearr[m][c] * (Asm * inv);
      }
      __syncthreads();
    }
  }
  grid.sync();

  // ---- P4: blocks 0..15: outv[d] += sum_{c chunk} wfin_m[c]*wv_m[c,d].
  if (gid < 16) {
    const int m = gid >> 2;
    const int cbase = (gid & 3) * 64;
    const float* wvarr[4] = {p.wv0, p.wv1, p.wv2, p.wv3};
    const float* wv = wvarr[m];
    float sacc = 0.f;
    #pragma unroll 8
    for (int i = 0; i < 64; ++i) {
      int c = cbase + i;
      sacc += ws[OFF_W + m * 256 + c] * wv[c * 256 + tid];
    }
    atomicAdd(&ws[OFF_OUTV + tid], sacc);
  }
  grid.sync();

  // ---- P5: block 0: r = layernorm(outv)*g_res + be_res.
  if (gid == 0) {
    float od = ws[OFF_OUTV + tid];
    float sr = od;
    for (int o = 32; o > 0; o >>= 1) sr += __shfl_down(sr, o, 64);
    if ((tid & 63) == 0) sh[tid >> 6] = sr;
    __syncthreads();
    float mu = (sh[0] + sh[1] + sh[2] + sh[3]) * (1.0f / 256.0f);
    __syncthreads();
    float dv = od - mu;
    sr = dv * dv;
    for (int o = 32; o > 0; o >>= 1) sr += __shfl_down(sr, o, 64);
    if ((tid & 63) == 0) sh[tid >> 6] = sr;
    __syncthreads();
    float var = (sh[0] + sh[1] + sh[2] + sh[3]) * (1.0f / 256.0f);
    ws[OFF_R + tid] = dv * rsqrtf(var + 1e-5f) * p.g_res[tid] + p.be_res[tid];
  }
  grid.sync();

  // ---- P6: blocks 0..31: gg += r-chunk @ w_geglu.
  if (gid < 32) {
    const int dt = gid >> 4;
    const int d0 = (gid & 15) * 16;
    float acc = 0.f;
    #pragma unroll
    for (int i = 0; i < 16; ++i) {
      int d = d0 + i;
      acc += ws[OFF_R + d] * p.w_geglu[d * 512 + dt * 256 + tid];
    }
    atomicAdd(&ws[OFF_GG + dt * 256 + tid], acc);
  }
  grid.sync();

  // ---- P7: blocks 0..15: ff += geglu(gg)-chunk @ w_ff2.
  if (gid < 16) {
    const int c0 = gid * 16;
    float acc = 0.f;
    #pragma unroll
    for (int i = 0; i < 16; ++i) {
      int c = c0 + i;
      float u = ws[OFF_GG + c];
      float gate = ws[OFF_GG + 256 + c];
      float f = u * 0.5f * gate * (1.0f + erff(gate * 0.70710678118654752f));
      acc += f * p.w_ff2[c * 256 + tid];
    }
    atomicAdd(&ws[OFF_FF + tid], acc);
  }
  grid.sync();

  // ---- P8: blocks 0..15: y += ff-chunk @ w_out.
  if (gid < 16) {
    const int d0 = gid * 16;
    float acc = 0.f;
    #pragma unroll
    for (int i = 0; i < 16; ++i) {
      int d = d0 + i;
      acc += ws[OFF_FF + d] * p.w_out[d * 256 + tid];
    }
    atomicAdd(&ws[OFF_Y + tid], acc);
  }
  grid.sync();

  // ---- P9: 512 blocks: broadcast y over spatial positions (2 float4 each).
  {
    #pragma unroll
    for (int k = 0; k < 2; ++k) {
      const int idx = gid * 512 + k * 256 + tid;  // 0..262143
      const int c = idx >> 10;
      float v = ws[OFF_Y + c];
      p.out4[idx] = make_float4(v, v, v, v);
    }
  }
}

// ===========================================================================
// Fallback multi-kernel pipeline (proven in round 2).
__global__ void kInit(const float* __restrict__ bt, const float* __restrict__ b_geglu,
                      const float* __restrict__ b_ff2, const float* __restrict__ b_out,
                      float* __restrict__ ws) {
  const int tid = threadIdx.x;  // 512
  ws[OFF_GG + tid] = b_geglu[tid];
  if (tid < 256) {
    ws[OFF_Q + tid] = bt[tid];
    ws[OFF_OUTV + tid] = 0.0f;
    ws[OFF_FF + tid] = b_ff2[tid];
    ws[OFF_Y + tid] = b_out[tid];
  }
  if (tid < 8) { ws[OFF_GUP + tid * 4] = 0.0f; }  // unused-slot safety
  if (tid < 64) { ws[OFF_GUP + tid] = 0.0f; ws[OFF_BUP] = ws[OFF_BUP]; }
}

__global__ void kQ(const float* __restrict__ t, const float* __restrict__ wt,
                   float* __restrict__ ws) {
  const int tid = threadIdx.x;
  const int c0 = blockIdx.x * 16;
  float acc = 0.f;
  #pragma unroll
  for (int i = 0; i < 16; ++i) {
    int c = c0 + i;
    acc += t[c] * wt[c * 256 + tid];
  }
  atomicAdd(&ws[OFF_Q + tid], acc);
}

__global__ void kU(const float* __restrict__ wk0, const float* __restrict__ wk1,
                   const float* __restrict__ wk2, const float* __restrict__ wk3,
                   const float* __restrict__ g0, const float* __restrict__ g1,
                   const float* __restrict__ g2, const float* __restrict__ g3,
                   const float* __restrict__ be0, const float* __restrict__ be1,
                   const float* __restrict__ be2, const float* __restrict__ be3,
                   float* __restrict__ ws) {
  const int b = blockIdx.x;
  const int m = b >> 3;
  const int c0 = (b & 7) * 32;
  const int tid = threadIdx.x;
  const int w = tid >> 6, lane = tid & 63;
  const float* wk = (m == 0) ? wk0 : (m == 1) ? wk1 : (m == 2) ? wk2 : wk3;
  const float* g  = (m == 0) ? g0  : (m == 1) ? g1  : (m == 2) ? g2  : g3;
  const float* be = (m == 0) ? be0 : (m == 1) ? be1 : (m == 2) ? be2 : be3;

  __shared__ float qsh[256];
  __shared__ float red[8];
  qsh[tid] = ws[OFF_Q + tid];
  __syncthreads();
  const float4 qv = ((const float4*)qsh)[lane];

  float lGU = 0.f, lBU = 0.f;
  #pragma unroll
  for (int r = 0; r < 8; ++r) {
    int c = c0 + w * 8 + r;
    float4 w4 = ((const float4*)(wk + c * 256))[lane];
    float s = w4.x * qv.x + w4.y * qv.y + w4.z * qv.z + w4.w * qv.w;
    for (int o = 32; o > 0; o >>= 1) s += __shfl_down(s, o, 64);
    if (lane == 0) {
      float u = s;
      float gu = g[c] * u;
      ws[OFF_GU + m * 256 + c] = gu;
      lGU += gu;
      lBU += be[c] * u;
    }
  }
  if (lane == 0) { red[w] = lGU; red[4 + w] = lBU; }
  __syncthreads();
  if (tid == 0) {
    ws[OFF_GUP + m * 8 + (b & 7)] = red[0] + red[1] + red[2] + red[3];
    ws[OFF_BUP + m * 8 + (b & 7)] = red[4] + red[5] + red[6] + red[7];
  }
}

__global__ void kB(const float* __restrict__ A0, const float* __restrict__ A1,
                   const float* __restrict__ A2, const float* __restrict__ A3,
                   float* __restrict__ ws) {
  const int b = blockIdx.x;
  const int m = b >> 6;
  const int jbase = (b & 63) * 64;
  const int tid = threadIdx.x;
  const int l = tid & 63;
  const int qq = tid >> 6;
  const float* A = (m == 0) ? A0 : (m == 1) ? A1 : (m == 2) ? A2 : A3;

  __shared__ float gu[256];
  __shared__ float p1[256], p2[256], p3[256];
  gu[tid] = ws[OFF_GU + m * 256 + tid];
  __syncthreads();

  float s1 = 0.f, s2 = 0.f, s3 = 0.f;
  const float* Abase = A + jbase + l;
  #pragma unroll 8
  for (int i = 0; i < 64; ++i) {
    int c = qq * 64 + i;
    float v = Abase[c * N_TOK];
    s1 += v;
    s2 += v * v;
    s3 += v * gu[c];
  }
  p1[tid] = s1; p2[tid] = s2; p3[tid] = s3;
  __syncthreads();
  if (tid < 64) {
    float S1 = p1[tid] + p1[tid + 64] + p1[tid + 128] + p1[tid + 192];
    float S2 = p2[tid] + p2[tid + 64] + p2[tid + 128] + p2[tid + 192];
    float S3 = p3[tid] + p3[tid + 64] + p3[tid + 128] + p3[tid + 192];
    float GU = 0.f, BU = 0.f;
    #pragma unroll
    for (int i = 0; i < 8; ++i) {
      GU += ws[OFF_GUP + m * 8 + i];
      BU += ws[OFF_BUP + m * 8 + i];
    }
    float mu   = S1 * (1.0f / 256.0f);
    float var  = S2 * (1.0f / 256.0f) - mu * mu;
    float rinv = rsqrtf(var + 1e-5f);
    float sim = 0.0625f * (rinv * (S3 - mu * GU) + BU);
    int gj = m * N_TOK + jbase + tid;
    ws[OFF_SIM + gj] = sim;
    ws[OFF_MU + gj] = mu;
    ws[OFF_RINV + gj] = rinv;
  }
}

__global__ void kC1(float* __restrict__ ws) {
  const int b = blockIdx.x;
  const int tid = threadIdx.x;
  const int base = b * 1024;
  __shared__ float sred[4];

  float v[4];
  float mx = -1e30f;
  #pragma unroll
  for (int i = 0; i < 4; ++i) {
    v[i] = ws[OFF_SIM + base + i * 256 + tid];
    mx = fmaxf(mx, v[i]);
  }
  for (int o = 32; o > 0; o >>= 1) mx = fmaxf(mx, __shfl_down(mx, o, 64));
  if ((tid & 63) == 0) sred[tid >> 6] = mx;
  __syncthreads();
  const float mxb = fmaxf(fmaxf(sred[0], sred[1]), fmaxf(sred[2], sred[3]));
  __syncthreads();

  float se = 0.f, srm = 0.f;
  #pragma unroll
  for (int i = 0; i < 4; ++i) {
    int idx = base + i * 256 + tid;
    float e = expf(v[i] - mxb);
    se += e;
    srm += e * ws[OFF_RINV + idx] * ws[OFF_MU + idx];
  }
  for (int o = 32; o > 0; o >>= 1) se += __shfl_down(se, o, 64);
  if ((tid & 63) == 0) sred[tid >> 6] = se;
  __syncthreads();
  float seT = sred[0] + sred[1] + sred[2] + sred[3];
  __syncthreads();
  for (int o = 32; o > 0; o >>= 1) srm += __shfl_down(srm, o, 64);
  if ((tid & 63) == 0) sred[tid >> 6] = srm;
  __syncthreads();
  if (tid == 0) {
    ws[OFF_BLK + b * 3 + 0] = mxb;
    ws[OFF_BLK + b * 3 + 1] = seT;
    ws[OFF_BLK + b * 3 + 2] = sred[0] + sred[1] + sred[2] + sred[3];
  }
}

__global__ void kC2(float* __restrict__ ws) {
  if (threadIdx.x != 0) return;
  float M = -1e30f;
  for (int b = 0; b < 16; ++b) M = fmaxf(M, ws[OFF_BLK + b * 3]);
  float S = 0.f, As[4] = {0, 0, 0, 0}, P[4] = {0, 0, 0, 0};
  for (int b = 0; b < 16; ++b) {
    float f = expf(ws[OFF_BLK + b * 3] - M);
    int m = b >> 2;
    S += ws[OFF_BLK + b * 3 + 1] * f;
    As[m] += ws[OFF_BLK + b * 3 + 1] * f;
    P[m] += ws[OFF_BLK + b * 3 + 2] * f;
  }
  float inv = 1.0f / S;
  ws[OFF_SOFT + 0] = M;
  ws[OFF_SOFT + 1] = inv;
  for (int m = 0; m < 4; ++m) {
    ws[OFF_SOFT + 2 + m] = As[m] * inv;
    ws[OFF_SOFT + 6 + m] = P[m] * inv;
  }
}

__global__ void kD(const float* __restrict__ A0, const float* __restrict__ A1,
                   const float* __restrict__ A2, const float* __restrict__ A3,
                   const float* __restrict__ g0, const float* __restrict__ g1,
                   const float* __restrict__ g2, const float* __restrict__ g3,
                   const float* __restrict__ be0, const float* __restrict__ be1,
                   const float* __restrict__ be2, const float* __restrict__ be3,
                   float* __restrict__ ws) {
  const int b = blockIdx.x;
  const int m = b >> 8;
  const int c = b & 255;
  const int tid = threadIdx.x;
  const float* A = (m == 0) ? A0 : (m == 1) ? A1 : (m == 2) ? A2 : A3;
  const float* row = A + c * N_TOK;
  const float M = ws[OFF_SOFT + 0];
  const float inv = ws[OFF_SOFT + 1];

  float s = 0.f;
  #pragma unroll 4
  for (int i = 0; i < 16; ++i) {
    int j = i * 256 + tid;
    int gj = m * N_TOK + j;
    float a = expf(ws[OFF_SIM + gj] - M) * ws[OFF_RINV + gj];
    s += a * row[j];
  }
  __shared__ float red[4];
  for (int o = 32; o > 0; o >>= 1) s += __shfl_down(s, o, 64);
  if ((tid & 63) == 0) red[tid >> 6] = s;
  __syncthreads();
  if (tid == 0) {
    float dot = (red[0] + red[1] + red[2] + red[3]) * inv;
    const float* g  = (m == 0) ? g0  : (m == 1) ? g1  : (m == 2) ? g2  : g3;
    const float* be = (m == 0) ? be0 : (m == 1) ? be1 : (m == 2) ? be2 : be3;
    ws[OFF_W + m * 256 + c] =
        g[c] * (dot - ws[OFF_SOFT + 6 + m]) + be[c] * ws[OFF_SOFT + 2 + m];
  }
}

__global__ void kE(const float* __restrict__ wv0, const float* __restrict__ wv1,
                   const float* __restrict__ wv2, const float* __restrict__ wv3,
                   float* __restrict__ ws) {
  const int b = blockIdx.x;
  const int m = b >> 2;
  const int cbase = (b & 3) * 64;
  const int d = threadIdx.x;
  const float* wv = (m == 0) ? wv0 : (m == 1) ? wv1 : (m == 2) ? wv2 : wv3;
  float s = 0.f;
  #pragma unroll 8
  for (int i = 0; i < 64; ++i) {
    int c = cbase + i;
    s += ws[OFF_W + m * 256 + c] * wv[c * 256 + d];
  }
  atomicAdd(&ws[OFF_OUTV + d], s);
}

__global__ void kT1(const float* __restrict__ g_res, const float* __restrict__ be_res,
                    float* __restrict__ ws) {
  const int tid = threadIdx.x;
  __shared__ float red[4];
  float od = ws[OFF_OUTV + tid];
  float s = od;
  for (int o = 32; o > 0; o >>= 1) s += __shfl_down(s, o, 64);
  if ((tid & 63) == 0) red[tid >> 6] = s;
  __syncthreads();
  float mu = (red[0] + red[1] + red[2] + red[3]) * (1.0f / 256.0f);
  __syncthreads();
  float dv = od - mu;
  s = dv * dv;
  for (int o = 32; o > 0; o >>= 1) s += __shfl_down(s, o, 64);
  if ((tid & 63) == 0) red[tid >> 6] = s;
  __syncthreads();
  float var = (red[0] + red[1] + red[2] + red[3]) * (1.0f / 256.0f);
  ws[OFF_R + tid] = dv * rsqrtf(var + 1e-5f) * g_res[tid] + be_res[tid];
}

__global__ void kT2(const float* __restrict__ w_geglu, float* __restrict__ ws) {
  const int b = blockIdx.x;
  const int dt = b >> 4;
  const int d0 = (b & 15) * 16;
  const int tid = threadIdx.x;
  float acc = 0.f;
  #pragma unroll
  for (int i = 0; i < 16; ++i) {
    int d = d0 + i;
    acc += ws[OFF_R + d] * w_geglu[d * 512 + dt * 256 + tid];
  }
  atomicAdd(&ws[OFF_GG + dt * 256 + tid], acc);
}

__global__ void kT3(const float* __restrict__ w_ff2, float* __restrict__ ws) {
  const int c0 = blockIdx.x * 16;
  const int tid = threadIdx.x;
  float acc = 0.f;
  #pragma unroll
  for (int i = 0; i < 16; ++i) {
    int c = c0 + i;
    float u = ws[OFF_GG + c];
    float gate = ws[OFF_GG + 256 + c];
    float f = u * 0.5f * gate * (1.0f + erff(gate * 0.70710678118654752f));
    acc += f * w_ff2[c * 256 + tid];
  }
  atomicAdd(&ws[OFF_FF + tid], acc);
}

__global__ void kT4(const float* __restrict__ w_out, float* __restrict__ ws) {
  const int d0 = blockIdx.x * 16;
  const int tid = threadIdx.x;
  float acc = 0.f;
  #pragma unroll
  for (int i = 0; i < 16; ++i) {
    int d = d0 + i;
    acc += ws[OFF_FF + d] * w_out[d * 256 + tid];
  }
  atomicAdd(&ws[OFF_Y + tid], acc);
}

__global__ void kG(const float* __restrict__ ws, float4* __restrict__ out4) {
  const int idx = blockIdx.x * 256 + threadIdx.x;
  const int c = idx >> 10;
  float v = ws[OFF_Y + c];
  out4[idx] = make_float4(v, v, v, v);
}

// ---------------------------------------------------------------------------
extern "C" void kernel_launch(void* const* d_in, const int* in_sizes, int n_in,
                              void* d_out, int out_size, void* d_ws, size_t ws_size,
                              hipStream_t stream) {
  Params p;
  p.x = (const float*)d_in[0];
  p.h = (const float*)d_in[1];
  p.s = (const float*)d_in[2];
  p.m = (const float*)d_in[3];
  p.t = (const float*)d_in[4];
  p.wt = (const float*)d_in[5];
  p.bt = (const float*)d_in[6];
  p.wk0 = (const float*)d_in[7];
  p.wv0 = (const float*)d_in[8];
  p.g0 = (const float*)d_in[9];
  p.be0 = (const float*)d_in[10];
  p.wk1 = (const float*)d_in[11];
  p.wv1 = (const float*)d_in[12];
  p.g1 = (const float*)d_in[13];
  p.be1 = (const float*)d_in[14];
  p.wk2 = (const float*)d_in[15];
  p.wv2 = (const float*)d_in[16];
  p.g2 = (const float*)d_in[17];
  p.be2 = (const float*)d_in[18];
  p.wk3 = (const float*)d_in[19];
  p.wv3 = (const float*)d_in[20];
  p.g3 = (const float*)d_in[21];
  p.be3 = (const float*)d_in[22];
  p.w_geglu = (const float*)d_in[23];
  p.b_geglu = (const float*)d_in[24];
  p.w_ff2 = (const float*)d_in[25];
  p.b_ff2 = (const float*)d_in[26];
  p.g_res = (const float*)d_in[27];
  p.be_res = (const float*)d_in[28];
  p.w_out = (const float*)d_in[29];
  p.b_out = (const float*)d_in[30];
  p.ws = (float*)d_ws;
  p.out4 = (float4*)d_out;
  float* ws = (float*)d_ws;

  // Deterministic dispatch: cooperative fused kernel if 512 blocks are
  // guaranteed co-resident (needs 2 blocks/CU on 256 CUs); else fallback.
  int nb = 0;
  hipError_t oe = hipOccupancyMaxActiveBlocksPerMultiprocessor(
      &nb, (const void*)fused, 256, 0);
  bool coop_ok = (oe == hipSuccess) && (nb >= 2);

  if (coop_ok) {
    void* args[] = {&p};
    hipError_t le = hipLaunchCooperativeKernel((const void*)fused, dim3(512),
                                               dim3(256), args, 0, stream);
    if (le == hipSuccess) return;
    // fall through to fallback on deterministic launch failure
  }

  kInit<<<dim3(1), dim3(512), 0, stream>>>(p.bt, p.b_geglu, p.b_ff2, p.b_out, ws);
  kQ<<<dim3(16), dim3(256), 0, stream>>>(p.t, p.wt, ws);
  kU<<<dim3(32), dim3(256), 0, stream>>>(p.wk0, p.wk1, p.wk2, p.wk3,
      p.g0, p.g1, p.g2, p.g3, p.be0, p.be1, p.be2, p.be3, ws);
  kB<<<dim3(256), dim3(256), 0, stream>>>(p.x, p.h, p.s, p.m, ws);
  kC1<<<dim3(16), dim3(256), 0, stream>>>(ws);
  kC2<<<dim3(1), dim3(64), 0, stream>>>(ws);
  kD<<<dim3(1024), dim3(256), 0, stream>>>(p.x, p.h, p.s, p.m,
      p.g0, p.g1, p.g2, p.g3, p.be0, p.be1, p.be2, p.be3, ws);
  kE<<<dim3(16), dim3(256), 0, stream>>>(p.wv0, p.wv1, p.wv2, p.wv3, ws);
  kT1<<<dim3(1), dim3(256), 0, stream>>>(p.g_res, p.be_res, ws);
  kT2<<<dim3(32), dim3(256), 0, stream>>>(p.w_geglu, ws);
  kT3<<<dim3(16), dim3(256), 0, stream>>>(p.w_ff2, ws);
  kT4<<<dim3(16), dim3(256), 0, stream>>>(p.w_out, ws);
  kG<<<dim3(1024), dim3(256), 0, stream>>>(ws, (float4*)d_out);
}

// Round 5
// 162.672 us; speedup vs baseline: 4.1215x; 4.1215x over previous
//
#include <hip/hip_runtime.h>
#include <math.h>

// Problem constants (B=1, C=256, W=64, N=4096, D=256)
#define N_TOK 4096

// workspace layout (float offsets)
#define OFF_GU    0        // 1024  : g[c]*u[c] per modality
#define OFF_GUP   1024     // 32    : GU partials (4 modalities x 8 blocks)
#define OFF_BUP   1056     // 32    : BU partials
#define OFF_PM    1088     // 256   : per flash-block local max
#define OFF_PSE   1344     // 256   : per flash-block sum(exp)
#define OFF_PSR   1600     // 256   : per flash-block sum(exp*rinv*mu)
#define OFF_OUTV  1856     // 256   : attention output vector (atomic, init 0)
#define OFF_GG    2112     // 512   : geglu pre-activation (atomic, init b_geglu)
#define OFF_Y     2624     // 256   : final channel vector (atomic, init b_out)
#define OFF_WS    3072     // 65536 : wsum partials [flash-block][c]
#define OFF_WC    69632    // 65536 : w_comb = w_ff2 @ w_out  [e][cout]

#define TSTRIDE 65         // LDS tile row stride (64 tokens + 1 pad -> 2-way max)

// ---------------------------------------------------------------------------
// K0: grid 289.
//   blocks 0..255  : w_comb row e = w_ff2[e,:] @ w_out            (row per block)
//   blocks 256..287: q = t@wt+bt (redundant) -> u = wk@q rows -> gu, GU/BU
//   block 288      : init atomic accumulators (outv=0, gg=b_geglu, y=b_out)
__global__ __launch_bounds__(256) void k0(
    const float* __restrict__ t, const float* __restrict__ wt,
    const float* __restrict__ bt,
    const float* __restrict__ wk0, const float* __restrict__ wk1,
    const float* __restrict__ wk2, const float* __restrict__ wk3,
    const float* __restrict__ g0, const float* __restrict__ g1,
    const float* __restrict__ g2, const float* __restrict__ g3,
    const float* __restrict__ be0, const float* __restrict__ be1,
    const float* __restrict__ be2, const float* __restrict__ be3,
    const float* __restrict__ w_ff2, const float* __restrict__ w_out,
    const float* __restrict__ b_geglu, const float* __restrict__ b_ff2,
    const float* __restrict__ b_out, float* __restrict__ ws) {
  const int gid = blockIdx.x;
  const int tid = threadIdx.x;
  __shared__ float sh[264];

  if (gid < 256) {
    // w_comb[e=gid][cout=tid] = sum_d w_ff2[e,d] * w_out[d,cout]
    sh[tid] = w_ff2[gid * 256 + tid];
    __syncthreads();
    float acc = 0.f;
    #pragma unroll 8
    for (int d = 0; d < 256; ++d) acc += sh[d] * w_out[d * 256 + tid];
    ws[OFF_WC + gid * 256 + tid] = acc;
  } else if (gid < 288) {
    const int local = gid - 256;
    const int m = local >> 3;
    const int c0 = (local & 7) * 32;
    const float* wk = (m == 0) ? wk0 : (m == 1) ? wk1 : (m == 2) ? wk2 : wk3;
    const float* g  = (m == 0) ? g0  : (m == 1) ? g1  : (m == 2) ? g2  : g3;
    const float* be = (m == 0) ? be0 : (m == 1) ? be1 : (m == 2) ? be2 : be3;

    float acc = bt[tid];
    #pragma unroll 8
    for (int c = 0; c < 256; ++c) acc += t[c] * wt[c * 256 + tid];
    sh[tid] = acc;               // q
    __syncthreads();

    const int w = tid >> 6, lane = tid & 63;
    const float4 qv = ((const float4*)sh)[lane];
    float lGU = 0.f, lBU = 0.f;
    #pragma unroll
    for (int r = 0; r < 8; ++r) {
      int c = c0 + w * 8 + r;
      float4 w4 = ((const float4*)(wk + c * 256))[lane];
      float sdot = w4.x * qv.x + w4.y * qv.y + w4.z * qv.z + w4.w * qv.w;
      for (int o = 32; o > 0; o >>= 1) sdot += __shfl_down(sdot, o, 64);
      if (lane == 0) {
        float u = sdot;
        float gu = g[c] * u;
        ws[OFF_GU + m * 256 + c] = gu;
        lGU += gu;
        lBU += be[c] * u;
      }
    }
    __syncthreads();
    if (lane == 0) { sh[256 + w] = lGU; sh[260 + w] = lBU; }
    __syncthreads();
    if (tid == 0) {
      ws[OFF_GUP + m * 8 + (local & 7)] = sh[256] + sh[257] + sh[258] + sh[259];
      ws[OFF_BUP + m * 8 + (local & 7)] = sh[260] + sh[261] + sh[262] + sh[263];
    }
  } else {
    ws[OFF_OUTV + tid] = 0.0f;
    ws[OFF_GG + tid] = b_geglu[tid];
    ws[OFF_GG + 256 + tid] = b_geglu[256 + tid];
    ws[OFF_Y + tid] = b_out[tid];
  }
}

// ---------------------------------------------------------------------------
// K2: flash-style single pass. grid 256 (64 blocks/modality, 64 tokens each).
// Stage tile[c][j] (stride-65) in LDS; per-token stats -> sim/mu/rinv;
// local softmax over 64 tokens; weighted channel sums wsum[c].
__global__ __launch_bounds__(256) void k2(
    const float* __restrict__ A0, const float* __restrict__ A1,
    const float* __restrict__ A2, const float* __restrict__ A3,
    float* __restrict__ ws) {
  const int b = blockIdx.x;
  const int m = b >> 6;
  const int jbase = (b & 63) * 64;
  const int tid = threadIdx.x;
  const float* A = (m == 0) ? A0 : (m == 1) ? A1 : (m == 2) ? A2 : A3;

  __shared__ float tile[256 * TSTRIDE];  // 66560 B
  __shared__ float gu_sh[256];
  __shared__ float r1[256], r2[256], r3[256];
  __shared__ float simj[64], rinvj[64], muj[64], alj[64];

  gu_sh[tid] = ws[OFF_GU + m * 256 + tid];

  // load tile: 16 iters, 16 rows x 16 float4 per iter
  {
    const int cr = tid >> 4;      // row within group of 16
    const int jf = tid & 15;      // float4 index within row
    #pragma unroll 4
    for (int it = 0; it < 16; ++it) {
      int c = it * 16 + cr;
      float4 v = *(const float4*)(A + c * N_TOK + jbase + jf * 4);
      int base = c * TSTRIDE + jf * 4;
      tile[base] = v.x; tile[base + 1] = v.y;
      tile[base + 2] = v.z; tile[base + 3] = v.w;
    }
  }
  __syncthreads();

  // per-token stats: j = tid&63, quarter q = tid>>6
  {
    const int j = tid & 63, q = tid >> 6;
    float s1 = 0.f, s2 = 0.f, s3 = 0.f;
    #pragma unroll 8
    for (int i = 0; i < 64; ++i) {
      int c = q * 64 + i;
      float v = tile[c * TSTRIDE + j];
      s1 += v; s2 += v * v; s3 += v * gu_sh[c];
    }
    r1[tid] = s1; r2[tid] = s2; r3[tid] = s3;
  }
  __syncthreads();
  if (tid < 64) {
    float S1 = r1[tid] + r1[tid + 64] + r1[tid + 128] + r1[tid + 192];
    float S2 = r2[tid] + r2[tid + 64] + r2[tid + 128] + r2[tid + 192];
    float S3 = r3[tid] + r3[tid + 64] + r3[tid + 128] + r3[tid + 192];
    float GU = 0.f, BU = 0.f;
    #pragma unroll
    for (int i = 0; i < 8; ++i) {
      GU += ws[OFF_GUP + m * 8 + i];
      BU += ws[OFF_BUP + m * 8 + i];
    }
    float mu = S1 * (1.0f / 256.0f);
    float var = S2 * (1.0f / 256.0f) - mu * mu;
    float rinv = rsqrtf(var + 1e-5f);
    simj[tid] = 0.0625f * (rinv * (S3 - mu * GU) + BU);
    muj[tid] = mu;
    rinvj[tid] = rinv;
  }
  __syncthreads();
  // local softmax partials over the 64 tokens (single wave, butterfly)
  if (tid < 64) {
    float sim = simj[tid];
    float mb = sim;
    #pragma unroll
    for (int o = 1; o < 64; o <<= 1) mb = fmaxf(mb, __shfl_xor(mb, o, 64));
    float e = expf(sim - mb);
    float al = e * rinvj[tid];
    alj[tid] = al;
    float se = e, sr = al * muj[tid];
    #pragma unroll
    for (int o = 1; o < 64; o <<= 1) {
      se += __shfl_xor(se, o, 64);
      sr += __shfl_xor(sr, o, 64);
    }
    if (tid == 0) {
      ws[OFF_PM + b] = mb;
      ws[OFF_PSE + b] = se;
      ws[OFF_PSR + b] = sr;
    }
  }
  __syncthreads();
  // weighted channel sums: c = tid
  {
    float wsum = 0.f;
    #pragma unroll 8
    for (int j = 0; j < 64; ++j) wsum += alj[j] * tile[tid * TSTRIDE + j];
    ws[OFF_WS + b * 256 + tid] = wsum;
  }
}

// ---------------------------------------------------------------------------
// K3: combine flash partials -> wfin chunk -> outv matvec partial.
// grid 16: mb = b>>2, cbase = (b&3)*64.
__global__ __launch_bounds__(256) void k3(
    const float* __restrict__ wv0, const float* __restrict__ wv1,
    const float* __restrict__ wv2, const float* __restrict__ wv3,
    const float* __restrict__ g0, const float* __restrict__ g1,
    const float* __restrict__ g2, const float* __restrict__ g3,
    const float* __restrict__ be0, const float* __restrict__ be1,
    const float* __restrict__ be2, const float* __restrict__ be3,
    float* __restrict__ ws) {
  const int b = blockIdx.x;
  const int mb = b >> 2;
  const int cbase = (b & 3) * 64;
  const int tid = threadIdx.x;
  const float* wv = (mb == 0) ? wv0 : (mb == 1) ? wv1 : (mb == 2) ? wv2 : wv3;
  const float* g  = (mb == 0) ? g0  : (mb == 1) ? g1  : (mb == 2) ? g2  : g3;
  const float* be = (mb == 0) ? be0 : (mb == 1) ? be1 : (mb == 2) ? be2 : be3;

  __shared__ float pm[256], pse[256], psr[256];
  __shared__ float red[4];
  __shared__ float wfin[64], fsh[64];
  __shared__ float sS, sAm, sPm;

  pm[tid] = ws[OFF_PM + tid];
  pse[tid] = ws[OFF_PSE + tid];
  psr[tid] = ws[OFF_PSR + tid];
  __syncthreads();

  // M = global max
  float v = pm[tid];
  for (int o = 32; o > 0; o >>= 1) v = fmaxf(v, __shfl_down(v, o, 64));
  if ((tid & 63) == 0) red[tid >> 6] = v;
  __syncthreads();
  const float M = fmaxf(fmaxf(red[0], red[1]), fmaxf(red[2], red[3]));
  __syncthreads();

  const float f = expf(pm[tid] - M);
  const float fse = f * pse[tid];
  const bool mine = (tid >> 6) == mb;

  // S (all blocks)
  v = fse;
  for (int o = 32; o > 0; o >>= 1) v += __shfl_down(v, o, 64);
  if ((tid & 63) == 0) red[tid >> 6] = v;
  __syncthreads();
  if (tid == 0) sS = red[0] + red[1] + red[2] + red[3];
  __syncthreads();
  // A_m (this modality)
  v = mine ? fse : 0.f;
  for (int o = 32; o > 0; o >>= 1) v += __shfl_down(v, o, 64);
  if ((tid & 63) == 0) red[tid >> 6] = v;
  __syncthreads();
  if (tid == 0) sAm = red[0] + red[1] + red[2] + red[3];
  __syncthreads();
  // P_m (this modality)
  v = mine ? f * psr[tid] : 0.f;
  for (int o = 32; o > 0; o >>= 1) v += __shfl_down(v, o, 64);
  if ((tid & 63) == 0) red[tid >> 6] = v;
  __syncthreads();
  if (tid == 0) sPm = red[0] + red[1] + red[2] + red[3];
  if (tid < 64) fsh[tid] = expf(pm[mb * 64 + tid] - M);
  __syncthreads();

  const float invS = 1.0f / sS;

  // wfin chunk: thread (c_l = tid&63, bg = tid>>6) sums 16 flash blocks
  {
    const int c_l = tid & 63, bg = tid >> 6;
    float part = 0.f;
    #pragma unroll 4
    for (int i = 0; i < 16; ++i) {
      int fb = bg * 16 + i;                  // block within modality
      part += fsh[fb] * ws[OFF_WS + (mb * 64 + fb) * 256 + cbase + c_l];
    }
    pse[tid] = part;                         // reuse as scratch
  }
  __syncthreads();
  if (tid < 64) {
    float dot = (pse[tid] + pse[tid + 64] + pse[tid + 128] + pse[tid + 192]) * invS;
    int c = cbase + tid;
    wfin[tid] = g[c] * (dot - sPm * invS) + be[c] * (sAm * invS);
  }
  __syncthreads();

  // outv partial: d = tid over the 64-c chunk
  {
    float acc = 0.f;
    #pragma unroll 8
    for (int i = 0; i < 64; ++i) acc += wfin[i] * wv[(cbase + i) * 256 + tid];
    atomicAdd(&ws[OFF_OUTV + tid], acc);
  }
}

// ---------------------------------------------------------------------------
// K4: LN (redundant per block) + geglu matvec partial. grid 32.
__global__ __launch_bounds__(256) void k4(
    const float* __restrict__ g_res, const float* __restrict__ be_res,
    const float* __restrict__ w_geglu, float* __restrict__ ws) {
  const int gid = blockIdx.x;
  const int tid = threadIdx.x;
  __shared__ float r_sh[256];
  __shared__ float red[4];

  float od = ws[OFF_OUTV + tid];
  float v = od;
  for (int o = 32; o > 0; o >>= 1) v += __shfl_down(v, o, 64);
  if ((tid & 63) == 0) red[tid >> 6] = v;
  __syncthreads();
  float mu = (red[0] + red[1] + red[2] + red[3]) * (1.0f / 256.0f);
  __syncthreads();
  float dv = od - mu;
  v = dv * dv;
  for (int o = 32; o > 0; o >>= 1) v += __shfl_down(v, o, 64);
  if ((tid & 63) == 0) red[tid >> 6] = v;
  __syncthreads();
  float var = (red[0] + red[1] + red[2] + red[3]) * (1.0f / 256.0f);
  r_sh[tid] = dv * rsqrtf(var + 1e-5f) * g_res[tid] + be_res[tid];
  __syncthreads();

  const int dt = gid >> 4;
  const int d0 = (gid & 15) * 16;
  float acc = 0.f;
  #pragma unroll
  for (int i = 0; i < 16; ++i) {
    int d = d0 + i;
    acc += r_sh[d] * w_geglu[d * 512 + dt * 256 + tid];
  }
  atomicAdd(&ws[OFF_GG + dt * 256 + tid], acc);
}

// ---------------------------------------------------------------------------
// K5: grid 32. blocks 0..15: y += geglu(gg)-chunk @ w_comb;
//     blocks 16..31: y += b_ff2-chunk @ w_out.
__global__ __launch_bounds__(256) void k5(
    const float* __restrict__ b_ff2, const float* __restrict__ w_out,
    float* __restrict__ ws) {
  const int gid = blockIdx.x;
  const int tid = threadIdx.x;
  float acc = 0.f;
  if (gid < 16) {
    const int e0 = gid * 16;
    #pragma unroll
    for (int i = 0; i < 16; ++i) {
      int e = e0 + i;
      float u = ws[OFF_GG + e];
      float gate = ws[OFF_GG + 256 + e];
      float ffin = u * 0.5f * gate * (1.0f + erff(gate * 0.70710678118654752f));
      acc += ffin * ws[OFF_WC + e * 256 + tid];
    }
  } else {
    const int d0 = (gid - 16) * 16;
    #pragma unroll
    for (int i = 0; i < 16; ++i) {
      int d = d0 + i;
      acc += b_ff2[d] * w_out[d * 256 + tid];
    }
  }
  atomicAdd(&ws[OFF_Y + tid], acc);
}

// ---------------------------------------------------------------------------
// K6: broadcast y over spatial positions. grid 512, 2 float4 each.
__global__ __launch_bounds__(256) void k6(const float* __restrict__ ws,
                                          float4* __restrict__ out4) {
  const int gid = blockIdx.x;
  const int tid = threadIdx.x;
  #pragma unroll
  for (int k = 0; k < 2; ++k) {
    const int idx = gid * 512 + k * 256 + tid;  // 0..262143
    const int c = idx >> 10;
    float v = ws[OFF_Y + c];
    out4[idx] = make_float4(v, v, v, v);
  }
}

// ---------------------------------------------------------------------------
extern "C" void kernel_launch(void* const* d_in, const int* in_sizes, int n_in,
                              void* d_out, int out_size, void* d_ws, size_t ws_size,
                              hipStream_t stream) {
  const float* x = (const float*)d_in[0];
  const float* h = (const float*)d_in[1];
  const float* s = (const float*)d_in[2];
  const float* m = (const float*)d_in[3];
  const float* t = (const float*)d_in[4];
  const float* wt = (const float*)d_in[5];
  const float* bt = (const float*)d_in[6];
  const float* wk_x = (const float*)d_in[7];
  const float* wv_x = (const float*)d_in[8];
  const float* g_x = (const float*)d_in[9];
  const float* be_x = (const float*)d_in[10];
  const float* wk_h = (const float*)d_in[11];
  const float* wv_h = (const float*)d_in[12];
  const float* g_h = (const float*)d_in[13];
  const float* be_h = (const float*)d_in[14];
  const float* wk_s = (const float*)d_in[15];
  const float* wv_s = (const float*)d_in[16];
  const float* g_s = (const float*)d_in[17];
  const float* be_s = (const float*)d_in[18];
  const float* wk_m = (const float*)d_in[19];
  const float* wv_m = (const float*)d_in[20];
  const float* g_m = (const float*)d_in[21];
  const float* be_m = (const float*)d_in[22];
  const float* w_geglu = (const float*)d_in[23];
  const float* b_geglu = (const float*)d_in[24];
  const float* w_ff2 = (const float*)d_in[25];
  const float* b_ff2 = (const float*)d_in[26];
  const float* g_res = (const float*)d_in[27];
  const float* be_res = (const float*)d_in[28];
  const float* w_out = (const float*)d_in[29];
  const float* b_out = (const float*)d_in[30];
  float* ws = (float*)d_ws;

  k0<<<dim3(289), dim3(256), 0, stream>>>(t, wt, bt,
      wk_x, wk_h, wk_s, wk_m, g_x, g_h, g_s, g_m, be_x, be_h, be_s, be_m,
      w_ff2, w_out, b_geglu, b_ff2, b_out, ws);
  k2<<<dim3(256), dim3(256), 0, stream>>>(x, h, s, m, ws);
  k3<<<dim3(16), dim3(256), 0, stream>>>(wv_x, wv_h, wv_s, wv_m,
      g_x, g_h, g_s, g_m, be_x, be_h, be_s, be_m, ws);
  k4<<<dim3(32), dim3(256), 0, stream>>>(g_res, be_res, w_geglu, ws);
  k5<<<dim3(32), dim3(256), 0, stream>>>(b_ff2, w_out, ws);
  k6<<<dim3(512), dim3(256), 0, stream>>>(ws, (float4*)d_out);
}